// Round 5
// baseline (1278.092 us; speedup 1.0000x reference)
//
#include <hip/hip_runtime.h>
#include <hip/hip_bf16.h>

// GAT: 3 layers. N=50000 nodes, E=800000 edges, H=4 heads.
// R7: GEMM = m97-style 2-barrier K-loop, bf16 hi/lo split A/B.
// R8/R10 (FAILED): gather restructures regressed vs compiler-pipelined
// simple loop; FETCH stuck at 410MB = 8 XCD x 51MB z (full-row random
// gather duplicates z into every XCD L2).
// R11: column-sliced XCD-affine gather. alpha precomputed per edge
// (4 head-planes) by a barrier-free wave-per-node kernel; gathers are
// (node, 32-col slice) waves, slice = blockIdx&7 ~ XCD (round-robin),
// so each XCD touches only 6.4MB of z. Zero barriers, zero LDS in the
// gather path. elr2 back to its own kernel.
// R12: resubmit of R11 (container infra failure, no counters returned).

#define NN 50000
#define NE 800000
#define NH_HEADS 4

typedef __attribute__((ext_vector_type(8))) short short8;
typedef __attribute__((ext_vector_type(4))) float floatx4;

__device__ inline float bf2f(short s) {
    union { unsigned u; float f; } v; v.u = ((unsigned)(unsigned short)s) << 16;
    return v.f;
}
__device__ inline short f2bf_rne(float x) {
    union { float f; unsigned u; } v; v.f = x;
    unsigned r = v.u + 0x7fff + ((v.u >> 16) & 1);
    return (short)(r >> 16);
}
// truncation hi/lo split: hi = trunc16(x), lo = trunc16(x - hi)
__device__ inline void split1(float x, short& h, short& l) {
    union { float f; unsigned u; } v; v.f = x;
    h = (short)(v.u >> 16);
    union { float f; unsigned u; } rv; rv.f = v.f - bf2f(h);
    l = (short)(rv.u >> 16);
}

// async 16B/lane global->LDS; lds base must be wave-uniform (dest = base + lane*16)
__device__ inline void load_lds16(const short* g, short* l) {
    __builtin_amdgcn_global_load_lds(
        (const __attribute__((address_space(1))) void*)g,
        (__attribute__((address_space(3))) void*)l, 16, 0, 0);
}

// ---------------- CSR build ----------------

__global__ void hist_kernel(const int* __restrict__ dst, int* __restrict__ deg, int E) {
    int e = blockIdx.x * 256 + threadIdx.x;
    if (e < E) atomicAdd(&deg[dst[e]], 1);
}

__global__ void scan_block_kernel(const int* __restrict__ deg, int* __restrict__ offs,
                                  int* __restrict__ bsums, int n) {
    __shared__ int s[256];
    int tid = threadIdx.x;
    int i = blockIdx.x * 256 + tid;
    int v = (i < n) ? deg[i] : 0;
    s[tid] = v;
    __syncthreads();
    for (int off = 1; off < 256; off <<= 1) {
        int x = (tid >= off) ? s[tid - off] : 0;
        __syncthreads();
        s[tid] += x;
        __syncthreads();
    }
    if (i < n) offs[i] = s[tid] - v;
    if (tid == 255) bsums[blockIdx.x] = s[255];
}

__global__ void scan_sums_kernel(const int* __restrict__ bsums, int* __restrict__ boffs, int nb) {
    __shared__ int s[256];
    int tid = threadIdx.x;
    int v = (tid < nb) ? bsums[tid] : 0;
    s[tid] = v;
    __syncthreads();
    for (int off = 1; off < 256; off <<= 1) {
        int x = (tid >= off) ? s[tid - off] : 0;
        __syncthreads();
        s[tid] += x;
        __syncthreads();
    }
    boffs[tid] = s[tid] - v;
}

__global__ void add_offs_kernel(int* __restrict__ offs, const int* __restrict__ boffs,
                                int* __restrict__ cursor, int n, int total) {
    int i = blockIdx.x * 256 + threadIdx.x;
    if (i < n) {
        int o = offs[i] + boffs[blockIdx.x];
        offs[i] = o;
        cursor[i] = o;
    }
    if (i == 0) offs[n] = total;
}

__global__ void scatter_kernel(const int* __restrict__ src, const int* __restrict__ dst,
                               int* __restrict__ cursor, int* __restrict__ psrc, int E) {
    int e = blockIdx.x * 256 + threadIdx.x;
    if (e < E) {
        int p = atomicAdd(&cursor[dst[e]], 1);
        psrc[p] = src[e];
    }
}

// ---------------- A (row-major fp32) -> row-major bf16 hi/lo ----------------

__global__ __launch_bounds__(256) void splitA_rm(const float* __restrict__ A,
                                                 short* __restrict__ hi,
                                                 short* __restrict__ lo,
                                                 int total8) {
    int tid = blockIdx.x * 256 + threadIdx.x;
    if (tid >= total8) return;
    const float* p = A + (size_t)tid * 8;
    float4 x0 = ((const float4*)p)[0];
    float4 x1 = ((const float4*)p)[1];
    float xs[8] = {x0.x, x0.y, x0.z, x0.w, x1.x, x1.y, x1.z, x1.w};
    short8 hv, lv;
#pragma unroll
    for (int j = 0; j < 8; ++j) { short h, l; split1(xs[j], h, l); hv[j] = h; lv[j] = l; }
    ((short8*)hi)[tid] = hv;
    ((short8*)lo)[tid] = lv;
}

// ---------------- B -> bf16 hi/lo in MFMA B-fragment order ----------------

__global__ __launch_bounds__(256) void splitB_kernel(const float* __restrict__ B,
                                                     short* __restrict__ hi,
                                                     short* __restrict__ lo,
                                                     int K, int N) {
    int tid = blockIdx.x * 256 + threadIdx.x;
    int NG = N >> 4;
    int total = (K >> 5) * NG * 64;
    if (tid >= total) return;
    int lane = tid & 63;
    int rc = tid >> 6;
    int g = rc % NG, c = rc / NG;
    int n = g * 16 + (lane & 15);
    int k = c * 32 + (lane >> 4) * 8;
    short8 hv, lv;
#pragma unroll
    for (int j = 0; j < 8; ++j) {
        float x = B[(size_t)(k + j) * N + n];
        short h = f2bf_rne(x);
        hv[j] = h;
        lv[j] = f2bf_rne(x - bf2f(h));
    }
    ((short8*)hi)[tid] = hv;
    ((short8*)lo)[tid] = lv;
}

// permuted-W2: Bp[h*256+k, c] = W2[k, h*256+c]; K=1024, N=256
__global__ __launch_bounds__(256) void splitB2_kernel(const float* __restrict__ W2,
                                                      short* __restrict__ hi,
                                                      short* __restrict__ lo) {
    int tid = blockIdx.x * 256 + threadIdx.x;
    const int NG = 16;
    int total = (1024 >> 5) * NG * 64;   // 32768
    if (tid >= total) return;
    int lane = tid & 63;
    int rc = tid >> 6;
    int g = rc % NG, c = rc / NG;
    int n = g * 16 + (lane & 15);
    int kk = c * 32 + (lane >> 4) * 8;
    short8 hv, lv;
#pragma unroll
    for (int j = 0; j < 8; ++j) {
        int kg = kk + j;
        int h = kg >> 8, k = kg & 255;
        float x = W2[(size_t)k * 1024 + h * 256 + n];
        short hb = f2bf_rne(x);
        hv[j] = hb;
        lv[j] = f2bf_rne(x - bf2f(hb));
    }
    ((short8*)hi)[tid] = hv;
    ((short8*)lo)[tid] = lv;
}

// ---------------- MFMA GEMM, N=256, A via async LDS staging ----------------

__device__ inline floatx4 mfma16(short8 a, short8 b, floatx4 c) {
    return __builtin_amdgcn_mfma_f32_16x16x32_bf16(a, b, c, 0, 0, 0);
}

__global__ __launch_bounds__(256) void gemm_n256l(const short* __restrict__ Ahi,
                                                  const short* __restrict__ Alo,
                                                  const short* __restrict__ Bh,
                                                  const short* __restrict__ Bl,
                                                  const float* __restrict__ bias4,
                                                  float* __restrict__ C,
                                                  int M, int K) {
    int KC = K >> 5;
    __shared__ short AhL[2048];   // 4 m-tiles x 64 lanes x 8 shorts = 4 KB
    __shared__ short AlL[2048];
    int t = threadIdx.x;
    int lane = t & 63;
    int w = t >> 6;
    int bm = blockIdx.x * 64;
    int g0 = w * 4;
    const short8* pBh = (const short8*)Bh;
    const short8* pBl = (const short8*)Bl;

    floatx4 acc[4][4] = {};

    int row = bm + (w << 4) + (lane & 15);
    if (row >= M) row = M - 1;                    // clamp: junk rows never stored
    const short* gh = Ahi + (size_t)row * K + ((lane >> 4) << 3);
    const short* gl = Alo + (size_t)row * K + ((lane >> 4) << 3);
    short* lh = AhL + w * 512;                    // wave-uniform LDS base
    short* ll = AlL + w * 512;

    for (int c = 0; c < KC; ++c) {
        load_lds16(gh + (size_t)c * 32, lh);
        load_lds16(gl + (size_t)c * 32, ll);
        short8 bh[4], bl[4];
#pragma unroll
        for (int g = 0; g < 4; ++g) {
            bh[g] = pBh[((size_t)c * (256 / 16) + g0 + g) * 64 + lane];
            bl[g] = pBl[((size_t)c * (256 / 16) + g0 + g) * 64 + lane];
        }
        __syncthreads();   // drains vmcnt: LDS staged, B regs ready
#pragma unroll
        for (int mt = 0; mt < 4; ++mt) {
            short8 ah = *(const short8*)(AhL + mt * 512 + lane * 8);
            short8 al = *(const short8*)(AlL + mt * 512 + lane * 8);
#pragma unroll
            for (int g = 0; g < 4; ++g) {
                acc[mt][g] = mfma16(ah, bh[g], acc[mt][g]);
                acc[mt][g] = mfma16(al, bh[g], acc[mt][g]);
                acc[mt][g] = mfma16(ah, bl[g], acc[mt][g]);
            }
        }
        __syncthreads();   // all LDS reads done before next overwrite
    }

    int rowb = bm + (lane >> 4) * 4;
    int colb = w * 64 + (lane & 15);
#pragma unroll
    for (int mt = 0; mt < 4; ++mt) {
#pragma unroll
        for (int r = 0; r < 4; ++r) {
            int rr = rowb + mt * 16 + r;
            if (rr < M) {
#pragma unroll
                for (int g = 0; g < 4; ++g) {
                    int col = colb + g * 16;
                    float v = acc[mt][g][r];
                    if (bias4) {
                        v = 0.25f * (v + bias4[col] + bias4[col + 256] +
                                     bias4[col + 512] + bias4[col + 768]);
                    }
                    C[(size_t)rr * 256 + col] = v;
                }
            }
        }
    }
}

// ---------------- attention score parts ----------------

__global__ __launch_bounds__(256) void elr_kernel(const float* __restrict__ z,
                                                  const float* __restrict__ al,
                                                  const float* __restrict__ ar,
                                                  float* __restrict__ el,
                                                  float* __restrict__ er,
                                                  int NH, int F) {
    int gid = blockIdx.x * 256 + threadIdx.x;
    int w = gid >> 6;
    int lane = threadIdx.x & 63;
    if (w >= NH) return;
    int n = w >> 2, h = w & 3;
    const float* zr = z + (size_t)n * (4 * F) + h * F;
    const float* alr = al + h * F;
    const float* arr = ar + h * F;
    float se = 0.f, sr = 0.f;
    for (int f = lane; f < F; f += 64) {
        float zv = zr[f];
        se += zv * alr[f];
        sr += zv * arr[f];
    }
#pragma unroll
    for (int off = 32; off > 0; off >>= 1) {
        se += __shfl_down(se, off);
        sr += __shfl_down(sr, off);
    }
    if (lane == 0) { el[w] = se; er[w] = sr; }
}

// val[h*256+k] = sum_j W2[k,h*256+j]*al2[h,j] ; var likewise with ar2
__global__ __launch_bounds__(256) void proj_av_kernel(const float* __restrict__ W2,
                                                      const float* __restrict__ al2,
                                                      const float* __restrict__ ar2,
                                                      float* __restrict__ val,
                                                      float* __restrict__ var_) {
    int gid = blockIdx.x * 256 + threadIdx.x;
    int w = gid >> 6;
    int lane = threadIdx.x & 63;
    if (w >= 1024) return;
    int h = w >> 8, k = w & 255;
    const float* wrow = W2 + (size_t)k * 1024 + h * 256;
    const float* ap = al2 + h * 256;
    const float* rp = ar2 + h * 256;
    float sv = 0.f, sr = 0.f;
    for (int j = lane; j < 256; j += 64) {
        float x = wrow[j];
        sv += x * ap[j];
        sr += x * rp[j];
    }
#pragma unroll
    for (int off = 32; off > 0; off >>= 1) {
        sv += __shfl_down(sv, off);
        sr += __shfl_down(sr, off);
    }
    if (lane == 0) { val[w] = sv; var_[w] = sr; }
}

// el[n,h] = h1[n,:]·val[h,:], er likewise
__global__ __launch_bounds__(256) void elr2_kernel(const float* __restrict__ h1,
                                                   const float* __restrict__ val,
                                                   const float* __restrict__ var_,
                                                   float* __restrict__ el,
                                                   float* __restrict__ er) {
    int gid = blockIdx.x * 256 + threadIdx.x;
    int w = gid >> 6;
    int lane = threadIdx.x & 63;
    if (w >= NN * 4) return;
    int n = w >> 2, h = w & 3;
    const float* hr = h1 + (size_t)n * 256;
    const float* vp = val + h * 256;
    const float* rp = var_ + h * 256;
    float se = 0.f, sr = 0.f;
    for (int k = lane; k < 256; k += 64) {
        float x = hr[k];
        se += x * vp[k];
        sr += x * rp[k];
    }
#pragma unroll
    for (int off = 32; off > 0; off >>= 1) {
        se += __shfl_down(se, off);
        sr += __shfl_down(sr, off);
    }
    if (lane == 0) { el[w] = se; er[w] = sr; }
}

// ---------------- aggregation: alpha precompute + sliced gather ----------------
// alpha_kernel: one wave per node, barrier-free. Writes p for each edge into
// 4 head-planes alpha[h*E + pos] (pos = CSR position) and den[n*4+h] via
// in-wave shfl_xor reduce (16 edge-lanes per head).

__global__ __launch_bounds__(256) void alpha_kernel(const float* __restrict__ el,
                                                    const float* __restrict__ er,
                                                    const int* __restrict__ offs,
                                                    const int* __restrict__ psrc,
                                                    float* __restrict__ alpha,
                                                    float* __restrict__ den) {
    int w = threadIdx.x >> 6, lane = threadIdx.x & 63;
    int n = blockIdx.x * 4 + w;
    if (n >= NN) return;
    int e16 = lane >> 2, hh = lane & 3;
    int beg = offs[n], end = offs[n + 1];
    float er_n = er[n * 4 + hh];
    float dsum = 0.f;
    for (int base = beg; base < end; base += 16) {
        int e = base + e16;
        if (e < end) {
            int s = psrc[e];
            float sc = el[s * 4 + hh] + er_n;
            sc = (sc > 0.f) ? sc : 0.2f * sc;
            float p = __expf(sc);
            alpha[(size_t)hh * NE + e] = p;
            dsum += p;
        }
    }
    dsum += __shfl_xor(dsum, 4);  dsum += __shfl_xor(dsum, 8);
    dsum += __shfl_xor(dsum, 16); dsum += __shfl_xor(dsum, 32);
    if (lane < 4) den[n * 4 + lane] = dsum;
}

// gslice_kernel: wave = (node, 32-col slice). slice = blockIdx&7 -> XCD
// (round-robin heuristic): each XCD touches only cols [sl*32,sl*32+32) of z
// (6.4MB, L2-resident). lanes: col = sl*32+(lane&31), eg = lane>>5 (2-way
// edge ILP), in-wave shfl reduce. outf!=null: fp32 out; else bf16 hi/lo.

__global__ __launch_bounds__(256) void gslice_kernel(const float* __restrict__ z,
                                                     const float* __restrict__ alpha,
                                                     const float* __restrict__ den,
                                                     const int* __restrict__ offs,
                                                     const int* __restrict__ psrc,
                                                     const float* __restrict__ bias,
                                                     float* __restrict__ outf,
                                                     short* __restrict__ ohi,
                                                     short* __restrict__ olo) {
    int bid = blockIdx.x;
    int sl = bid & 7;
    int w = threadIdx.x >> 6, lane = threadIdx.x & 63;
    int n = (bid >> 3) * 4 + w;
    if (n >= NN) return;
    int h = sl >> 1;
    int col = sl * 32 + (lane & 31);
    int eg = lane >> 5;
    int beg = offs[n], cnt = offs[n + 1] - beg;
    const int* sp = psrc + beg;
    const float* ap = alpha + (size_t)h * NE + beg;
    float acc = 0.f;
    for (int e = eg; e < cnt; e += 2) {
        int s = sp[e];
        float a = ap[e];
        acc += a * z[(size_t)s * 256 + col];
    }
    acc += __shfl_down(acc, 32);
    if (lane < 32) {
        float o = acc / fmaxf(den[n * 4 + h], 1e-9f) + bias[col];
        o = (o > 0.f) ? o : (__expf(o) - 1.f);
        if (outf) {
            outf[(size_t)n * 256 + col] = o;
        } else {
            short hv, lv;
            split1(o, hv, lv);
            ohi[(size_t)n * 256 + col] = hv;
            olo[(size_t)n * 256 + col] = lv;
        }
    }
}

// gsliceH_kernel: layer-2 variant, 4 head-accumulators per lane, writes
// bf16 hi/lo [N,1024] at n*1024 + h*256 + col. No bias, no activation.

__global__ __launch_bounds__(256) void gsliceH_kernel(const float* __restrict__ h1,
                                                      const float* __restrict__ alpha,
                                                      const float* __restrict__ den,
                                                      const int* __restrict__ offs,
                                                      const int* __restrict__ psrc,
                                                      short* __restrict__ ohi,
                                                      short* __restrict__ olo) {
    int bid = blockIdx.x;
    int sl = bid & 7;
    int w = threadIdx.x >> 6, lane = threadIdx.x & 63;
    int n = (bid >> 3) * 4 + w;
    if (n >= NN) return;
    int col = sl * 32 + (lane & 31);
    int eg = lane >> 5;
    int beg = offs[n], cnt = offs[n + 1] - beg;
    const int* sp = psrc + beg;
    const float* a0p = alpha + beg;
    const float* a1p = alpha + (size_t)NE + beg;
    const float* a2p = alpha + 2 * (size_t)NE + beg;
    const float* a3p = alpha + 3 * (size_t)NE + beg;
    float c0 = 0.f, c1 = 0.f, c2 = 0.f, c3 = 0.f;
    for (int e = eg; e < cnt; e += 2) {
        int s = sp[e];
        float v = h1[(size_t)s * 256 + col];
        c0 += a0p[e] * v;
        c1 += a1p[e] * v;
        c2 += a2p[e] * v;
        c3 += a3p[e] * v;
    }
    c0 += __shfl_down(c0, 32);
    c1 += __shfl_down(c1, 32);
    c2 += __shfl_down(c2, 32);
    c3 += __shfl_down(c3, 32);
    if (lane < 32) {
        float vals[4];
        vals[0] = c0 / fmaxf(den[n * 4 + 0], 1e-9f);
        vals[1] = c1 / fmaxf(den[n * 4 + 1], 1e-9f);
        vals[2] = c2 / fmaxf(den[n * 4 + 2], 1e-9f);
        vals[3] = c3 / fmaxf(den[n * 4 + 3], 1e-9f);
        size_t bo = (size_t)n * 1024 + col;
#pragma unroll
        for (int h = 0; h < 4; ++h) {
            short hv, lv;
            split1(vals[h], hv, lv);
            ohi[bo + h * 256] = hv;
            olo[bo + h * 256] = lv;
        }
    }
}

// fallback layer-2 aggregation (R0 baseline structure) when ws too small for
// the alpha tail buffer.

__global__ __launch_bounds__(256) void aggH_bf_fb(const float* __restrict__ h1,
                                                  const float* __restrict__ el,
                                                  const float* __restrict__ er,
                                                  const int* __restrict__ offs,
                                                  const int* __restrict__ psrc,
                                                  short* __restrict__ ohi,
                                                  short* __restrict__ olo) {
    int n = blockIdx.x, t = threadIdx.x;
    __shared__ float p_lds[64][4];
    __shared__ int src_lds[64];
    __shared__ float den_lds[4];
    if (t < 4) den_lds[t] = 0.f;
    int beg = offs[n], end = offs[n + 1];
    float a0 = 0.f, a1 = 0.f, a2 = 0.f, a3 = 0.f;
    int e_local = t >> 2, hh = t & 3;
    float er_n = er[n * 4 + hh];
    for (int base = beg; base < end; base += 64) {
        int cnt = min(64, end - base);
        __syncthreads();
        if (e_local < cnt) {
            int s = psrc[base + e_local];
            if (hh == 0) src_lds[e_local] = s;
            float sc = el[s * 4 + hh] + er_n;
            sc = (sc > 0.f) ? sc : 0.2f * sc;
            float p = __expf(sc);
            p_lds[e_local][hh] = p;
            atomicAdd(&den_lds[hh], p);
        }
        __syncthreads();
        for (int e = 0; e < cnt; ++e) {
            float v = h1[(size_t)src_lds[e] * 256 + t];
            a0 += p_lds[e][0] * v;
            a1 += p_lds[e][1] * v;
            a2 += p_lds[e][2] * v;
            a3 += p_lds[e][3] * v;
        }
    }
    __syncthreads();
    float vals[4];
    vals[0] = a0 / fmaxf(den_lds[0], 1e-9f);
    vals[1] = a1 / fmaxf(den_lds[1], 1e-9f);
    vals[2] = a2 / fmaxf(den_lds[2], 1e-9f);
    vals[3] = a3 / fmaxf(den_lds[3], 1e-9f);
    size_t base_o = (size_t)n * 1024 + t;
#pragma unroll
    for (int h = 0; h < 4; ++h) {
        short hv, lv;
        split1(vals[h], hv, lv);
        ohi[base_o + h * 256] = hv;
        olo[base_o + h * 256] = lv;
    }
}

// ---------------- launch ----------------

extern "C" void kernel_launch(void* const* d_in, const int* in_sizes, int n_in,
                              void* d_out, int out_size, void* d_ws, size_t ws_size,
                              hipStream_t stream) {
    const float* feat = (const float*)d_in[0];
    const float* W0 = (const float*)d_in[1];
    const float* al0 = (const float*)d_in[2];
    const float* ar0 = (const float*)d_in[3];
    const float* b0 = (const float*)d_in[4];
    const float* W1 = (const float*)d_in[5];
    const float* al1 = (const float*)d_in[6];
    const float* ar1 = (const float*)d_in[7];
    const float* b1 = (const float*)d_in[8];
    const float* W2 = (const float*)d_in[9];
    const float* al2 = (const float*)d_in[10];
    const float* ar2 = (const float*)d_in[11];
    const float* b2 = (const float*)d_in[12];
    const int* src = (const int*)d_in[13];
    const int* dst = (const int*)d_in[14];
    float* out = (float*)d_out;

    // ---- workspace layout (~263MB core + optional 13.6MB tail) ----
    float* slotA = (float*)d_ws;
    float* z = slotA;                                     // [N,256] fp32
    short* feathi = (short*)(slotA + (size_t)NN * 256);   // 50000*128 shorts
    short* featlo = feathi + (size_t)NN * 128;
    short* Ahi = (short*)slotA;                           // [N,1024] shorts (layer 2)
    short* Alo = Ahi + (size_t)NN * 1024;
    // alpha/den for L0/L1 in guaranteed slotA slack (beyond z+feat=76.8MB,
    // well inside slotA's 204.8MB; dead during L0/L1 aggregation)
    float* alphaA = slotA + 20000000;                     // 3.2M floats (12.8MB)
    float* denA = alphaA + (size_t)4 * NE;                // 200000
    float* slotB = slotA + (size_t)NN * 1024;
    short* h0hi = (short*)slotB;                          // 50000*256 shorts
    short* h0lo = h0hi + (size_t)NN * 256;
    float* h1 = slotB;                                    // [N,256] fp32 (layer 2)
    float* el = slotB + (size_t)NN * 256;                 // 200000
    float* er = el + (size_t)NN * NH_HEADS;               // 200000
    int* deg = (int*)(er + (size_t)NN * NH_HEADS);        // 50000
    int* offs = deg + NN;                                 // 50001 (+1 pad)
    int* cursor = offs + NN + 2;                          // 50000
    int* bsums = cursor + NN;                             // 256
    int* boffs = bsums + 256;                             // 256
    int* psrc = boffs + 256;                              // 800000 (+2 pad)
    short* Bh = (short*)(psrc + NE + 2);                  // 262144 shorts
    short* Bl = Bh + 262144;                              // 262144 shorts
    float* val = (float*)(Bl + 262144);                   // 1024
    float* var_ = val + 1024;                             // 1024
    // layer-2 alpha tail (guarded: slotA is Ahi/Alo during gsliceH)
    float* alphaT = var_ + 1024;                          // 3.2M floats
    float* denT = alphaT + (size_t)4 * NE;                // 200000
    size_t needT = (size_t)((char*)(denT + (size_t)NN * 4) - (char*)d_ws);
    bool sliceL2 = needT <= ws_size;

    // ---- CSR build (by dst) ----
    hipMemsetAsync(deg, 0, NN * sizeof(int), stream);
    hist_kernel<<<(NE + 255) / 256, 256, 0, stream>>>(dst, deg, NE);
    int nb = (NN + 255) / 256;
    scan_block_kernel<<<nb, 256, 0, stream>>>(deg, offs, bsums, NN);
    scan_sums_kernel<<<1, 256, 0, stream>>>(bsums, boffs, nb);
    add_offs_kernel<<<nb, 256, 0, stream>>>(offs, boffs, cursor, NN, NE);
    scatter_kernel<<<(NE + 255) / 256, 256, 0, stream>>>(src, dst, cursor, psrc, NE);

    int mb64 = (NN + 63) / 64;    // 782
    int nb4 = (NN + 3) / 4;       // 12500 (wave-per-node kernels)
    int gslice_grid = nb4 * 8;    // 100000 (node-quad x slice)

    // ---- layer 0: 128 -> 4x64, elu ----
    splitA_rm<<<(NN * 128 / 8 + 255) / 256, 256, 0, stream>>>(feat, feathi, featlo, NN * 128 / 8);
    splitB_kernel<<<(4096 + 255) / 256, 256, 0, stream>>>(W0, Bh, Bl, 128, 256);
    gemm_n256l<<<mb64, 256, 0, stream>>>(feathi, featlo, Bh, Bl, nullptr, z, NN, 128);
    elr_kernel<<<(NN * NH_HEADS) / 4, 256, 0, stream>>>(z, al0, ar0, el, er, NN * NH_HEADS, 64);
    alpha_kernel<<<nb4, 256, 0, stream>>>(el, er, offs, psrc, alphaA, denA);
    gslice_kernel<<<gslice_grid, 256, 0, stream>>>(z, alphaA, denA, offs, psrc, b0,
                                                   nullptr, h0hi, h0lo);

    // ---- layer 1: 256 -> 4x64, elu ----
    splitB_kernel<<<(8192 + 255) / 256, 256, 0, stream>>>(W1, Bh, Bl, 256, 256);
    gemm_n256l<<<mb64, 256, 0, stream>>>(h0hi, h0lo, Bh, Bl, nullptr, z, NN, 256);
    elr_kernel<<<(NN * NH_HEADS) / 4, 256, 0, stream>>>(z, al1, ar1, el, er, NN * NH_HEADS, 64);
    alpha_kernel<<<nb4, 256, 0, stream>>>(el, er, offs, psrc, alphaA, denA);
    gslice_kernel<<<gslice_grid, 256, 0, stream>>>(z, alphaA, denA, offs, psrc, b1,
                                                   h1, nullptr, nullptr);

    // ---- layer 2: score from aggregated h1, then project ----
    proj_av_kernel<<<256, 256, 0, stream>>>(W2, al2, ar2, val, var_);
    elr2_kernel<<<NN, 256, 0, stream>>>(h1, val, var_, el, er);
    if (sliceL2) {
        alpha_kernel<<<nb4, 256, 0, stream>>>(el, er, offs, psrc, alphaT, denT);
        gsliceH_kernel<<<gslice_grid, 256, 0, stream>>>(h1, alphaT, denT, offs, psrc,
                                                        Ahi, Alo);
    } else {
        aggH_bf_fb<<<NN, 256, 0, stream>>>(h1, el, er, offs, psrc, Ahi, Alo);
    }
    splitB2_kernel<<<(32768 + 255) / 256, 256, 0, stream>>>(W2, Bh, Bl);
    gemm_n256l<<<mb64, 256, 0, stream>>>(Ahi, Alo, Bh, Bl, b2, out, NN, 1024);
}

// Round 6
// 834.886 us; speedup vs baseline: 1.5309x; 1.5309x over previous
//
#include <hip/hip_runtime.h>
#include <hip/hip_bf16.h>

// GAT: 3 layers. N=50000 nodes, E=800000 edges, H=4 heads.
// R7: GEMM = m97-style 2-barrier K-loop, bf16 hi/lo split A/B.
// R8/R10/R11 (FAILED): every manual gather restructure reduced in-flight
// loads vs the compiler-pipelined per-thread loop (R0: 145us, 4.3TB/s,
// VGPR32 ~ 8 loads in flight). R11's 32-col slice (6.4MB) also missed
// L2 (4MiB/XCD) permanently. Lesson: keep the R0 gather loop untouched.
// R13: best-of combination. R0 aggregation kernels exactly; elr fused
// into the GEMM epilogue (wave w = head w holds the full col-block of
// every row -> 4 FMA + 4 shfl_xor per row); elr2 fused into agg_kernel
// epilogue (benched in R2/R3). Removes 3 dispatches + 2x 51MB z reads.

#define NN 50000
#define NE 800000
#define NH_HEADS 4

typedef __attribute__((ext_vector_type(8))) short short8;
typedef __attribute__((ext_vector_type(4))) float floatx4;

__device__ inline float bf2f(short s) {
    union { unsigned u; float f; } v; v.u = ((unsigned)(unsigned short)s) << 16;
    return v.f;
}
__device__ inline short f2bf_rne(float x) {
    union { float f; unsigned u; } v; v.f = x;
    unsigned r = v.u + 0x7fff + ((v.u >> 16) & 1);
    return (short)(r >> 16);
}
// truncation hi/lo split: hi = trunc16(x), lo = trunc16(x - hi)
__device__ inline void split1(float x, short& h, short& l) {
    union { float f; unsigned u; } v; v.f = x;
    h = (short)(v.u >> 16);
    union { float f; unsigned u; } rv; rv.f = v.f - bf2f(h);
    l = (short)(rv.u >> 16);
}

// async 16B/lane global->LDS; lds base must be wave-uniform (dest = base + lane*16)
__device__ inline void load_lds16(const short* g, short* l) {
    __builtin_amdgcn_global_load_lds(
        (const __attribute__((address_space(1))) void*)g,
        (__attribute__((address_space(3))) void*)l, 16, 0, 0);
}

// ---------------- CSR build ----------------

__global__ void hist_kernel(const int* __restrict__ dst, int* __restrict__ deg, int E) {
    int e = blockIdx.x * 256 + threadIdx.x;
    if (e < E) atomicAdd(&deg[dst[e]], 1);
}

__global__ void scan_block_kernel(const int* __restrict__ deg, int* __restrict__ offs,
                                  int* __restrict__ bsums, int n) {
    __shared__ int s[256];
    int tid = threadIdx.x;
    int i = blockIdx.x * 256 + tid;
    int v = (i < n) ? deg[i] : 0;
    s[tid] = v;
    __syncthreads();
    for (int off = 1; off < 256; off <<= 1) {
        int x = (tid >= off) ? s[tid - off] : 0;
        __syncthreads();
        s[tid] += x;
        __syncthreads();
    }
    if (i < n) offs[i] = s[tid] - v;
    if (tid == 255) bsums[blockIdx.x] = s[255];
}

__global__ void scan_sums_kernel(const int* __restrict__ bsums, int* __restrict__ boffs, int nb) {
    __shared__ int s[256];
    int tid = threadIdx.x;
    int v = (tid < nb) ? bsums[tid] : 0;
    s[tid] = v;
    __syncthreads();
    for (int off = 1; off < 256; off <<= 1) {
        int x = (tid >= off) ? s[tid - off] : 0;
        __syncthreads();
        s[tid] += x;
        __syncthreads();
    }
    boffs[tid] = s[tid] - v;
}

__global__ void add_offs_kernel(int* __restrict__ offs, const int* __restrict__ boffs,
                                int* __restrict__ cursor, int n, int total) {
    int i = blockIdx.x * 256 + threadIdx.x;
    if (i < n) {
        int o = offs[i] + boffs[blockIdx.x];
        offs[i] = o;
        cursor[i] = o;
    }
    if (i == 0) offs[n] = total;
}

__global__ void scatter_kernel(const int* __restrict__ src, const int* __restrict__ dst,
                               int* __restrict__ cursor, int* __restrict__ psrc, int E) {
    int e = blockIdx.x * 256 + threadIdx.x;
    if (e < E) {
        int p = atomicAdd(&cursor[dst[e]], 1);
        psrc[p] = src[e];
    }
}

// ---------------- A (row-major fp32) -> row-major bf16 hi/lo ----------------

__global__ __launch_bounds__(256) void splitA_rm(const float* __restrict__ A,
                                                 short* __restrict__ hi,
                                                 short* __restrict__ lo,
                                                 int total8) {
    int tid = blockIdx.x * 256 + threadIdx.x;
    if (tid >= total8) return;
    const float* p = A + (size_t)tid * 8;
    float4 x0 = ((const float4*)p)[0];
    float4 x1 = ((const float4*)p)[1];
    float xs[8] = {x0.x, x0.y, x0.z, x0.w, x1.x, x1.y, x1.z, x1.w};
    short8 hv, lv;
#pragma unroll
    for (int j = 0; j < 8; ++j) { short h, l; split1(xs[j], h, l); hv[j] = h; lv[j] = l; }
    ((short8*)hi)[tid] = hv;
    ((short8*)lo)[tid] = lv;
}

// ---------------- B -> bf16 hi/lo in MFMA B-fragment order ----------------
// offset (short8) = (c*(N/16)+g)*64 + lane ; lane=(n&15)+16*((k&31)>>3), j=k&7

__global__ __launch_bounds__(256) void splitB_kernel(const float* __restrict__ B,
                                                     short* __restrict__ hi,
                                                     short* __restrict__ lo,
                                                     int K, int N) {
    int tid = blockIdx.x * 256 + threadIdx.x;
    int NG = N >> 4;
    int total = (K >> 5) * NG * 64;
    if (tid >= total) return;
    int lane = tid & 63;
    int rc = tid >> 6;
    int g = rc % NG, c = rc / NG;
    int n = g * 16 + (lane & 15);
    int k = c * 32 + (lane >> 4) * 8;
    short8 hv, lv;
#pragma unroll
    for (int j = 0; j < 8; ++j) {
        float x = B[(size_t)(k + j) * N + n];
        short h = f2bf_rne(x);
        hv[j] = h;
        lv[j] = f2bf_rne(x - bf2f(h));
    }
    ((short8*)hi)[tid] = hv;
    ((short8*)lo)[tid] = lv;
}

// permuted-W2: Bp[h*256+k, c] = W2[k, h*256+c]; K=1024, N=256
__global__ __launch_bounds__(256) void splitB2_kernel(const float* __restrict__ W2,
                                                      short* __restrict__ hi,
                                                      short* __restrict__ lo) {
    int tid = blockIdx.x * 256 + threadIdx.x;
    const int NG = 16;
    int total = (1024 >> 5) * NG * 64;   // 32768
    if (tid >= total) return;
    int lane = tid & 63;
    int rc = tid >> 6;
    int g = rc % NG, c = rc / NG;
    int n = g * 16 + (lane & 15);
    int kk = c * 32 + (lane >> 4) * 8;
    short8 hv, lv;
#pragma unroll
    for (int j = 0; j < 8; ++j) {
        int kg = kk + j;
        int h = kg >> 8, k = kg & 255;
        float x = W2[(size_t)k * 1024 + h * 256 + n];
        short hb = f2bf_rne(x);
        hv[j] = hb;
        lv[j] = f2bf_rne(x - bf2f(hb));
    }
    ((short8*)hi)[tid] = hv;
    ((short8*)lo)[tid] = lv;
}

// ---------------- MFMA GEMM, N=256, A via async LDS staging ----------------
// block: 64 rows x 256 cols; wave w owns rows [bm,bm+64) x cols [w*64,(w+1)*64).
// Optional fused elr epilogue (alv!=null): wave w = head w computes
// el[n,w] = z[n, w*64..w*64+64) . alv[w], er likewise, via 4 FMA +
// 4-step shfl_xor reduce over the 16-lane col group per row.

__device__ inline floatx4 mfma16(short8 a, short8 b, floatx4 c) {
    return __builtin_amdgcn_mfma_f32_16x16x32_bf16(a, b, c, 0, 0, 0);
}

__global__ __launch_bounds__(256) void gemm_n256l(const short* __restrict__ Ahi,
                                                  const short* __restrict__ Alo,
                                                  const short* __restrict__ Bh,
                                                  const short* __restrict__ Bl,
                                                  const float* __restrict__ bias4,
                                                  float* __restrict__ C,
                                                  const float* __restrict__ alv,
                                                  const float* __restrict__ arv,
                                                  float* __restrict__ elo,
                                                  float* __restrict__ ero,
                                                  int M, int K) {
    int KC = K >> 5;
    __shared__ short AhL[2048];   // 4 m-tiles x 64 lanes x 8 shorts = 4 KB
    __shared__ short AlL[2048];
    int t = threadIdx.x;
    int lane = t & 63;
    int w = t >> 6;
    int bm = blockIdx.x * 64;
    int g0 = w * 4;
    const short8* pBh = (const short8*)Bh;
    const short8* pBl = (const short8*)Bl;

    floatx4 acc[4][4] = {};

    // staging source for this lane (m-tile w)
    int row = bm + (w << 4) + (lane & 15);
    if (row >= M) row = M - 1;                    // clamp: junk rows never stored
    const short* gh = Ahi + (size_t)row * K + ((lane >> 4) << 3);
    const short* gl = Alo + (size_t)row * K + ((lane >> 4) << 3);
    short* lh = AhL + w * 512;                    // wave-uniform LDS base
    short* ll = AlL + w * 512;

    for (int c = 0; c < KC; ++c) {
        load_lds16(gh + (size_t)c * 32, lh);
        load_lds16(gl + (size_t)c * 32, ll);
        short8 bh[4], bl[4];
#pragma unroll
        for (int g = 0; g < 4; ++g) {
            bh[g] = pBh[((size_t)c * (256 / 16) + g0 + g) * 64 + lane];
            bl[g] = pBl[((size_t)c * (256 / 16) + g0 + g) * 64 + lane];
        }
        __syncthreads();   // drains vmcnt: LDS staged, B regs ready
#pragma unroll
        for (int mt = 0; mt < 4; ++mt) {
            short8 ah = *(const short8*)(AhL + mt * 512 + lane * 8);
            short8 al = *(const short8*)(AlL + mt * 512 + lane * 8);
#pragma unroll
            for (int g = 0; g < 4; ++g) {
                acc[mt][g] = mfma16(ah, bh[g], acc[mt][g]);
                acc[mt][g] = mfma16(al, bh[g], acc[mt][g]);
                acc[mt][g] = mfma16(ah, bl[g], acc[mt][g]);
            }
        }
        __syncthreads();   // all LDS reads done before next overwrite
    }

    // C/D layout: col = lane&15, row = (lane>>4)*4 + reg
    int rowb = bm + (lane >> 4) * 4;
    int colb = w * 64 + (lane & 15);
#pragma unroll
    for (int mt = 0; mt < 4; ++mt) {
#pragma unroll
        for (int r = 0; r < 4; ++r) {
            int rr = rowb + mt * 16 + r;
            if (rr < M) {
#pragma unroll
                for (int g = 0; g < 4; ++g) {
                    int col = colb + g * 16;
                    float v = acc[mt][g][r];
                    if (bias4) {
                        v = 0.25f * (v + bias4[col] + bias4[col + 256] +
                                     bias4[col + 512] + bias4[col + 768]);
                    }
                    C[(size_t)rr * 256 + col] = v;
                }
            }
        }
    }

    // fused elr: el[rr,w] = sum_f z[rr, w*64+f]*alv[w*64+f] (f = (lane&15)+g*16)
    if (alv) {
        float alr[4], arr_[4];
#pragma unroll
        for (int g = 0; g < 4; ++g) {
            int f = w * 64 + (lane & 15) + g * 16;
            alr[g] = alv[f];
            arr_[g] = arv[f];
        }
#pragma unroll
        for (int mt = 0; mt < 4; ++mt) {
#pragma unroll
            for (int r = 0; r < 4; ++r) {
                float se = acc[mt][0][r] * alr[0] + acc[mt][1][r] * alr[1] +
                           acc[mt][2][r] * alr[2] + acc[mt][3][r] * alr[3];
                float sr = acc[mt][0][r] * arr_[0] + acc[mt][1][r] * arr_[1] +
                           acc[mt][2][r] * arr_[2] + acc[mt][3][r] * arr_[3];
                se += __shfl_xor(se, 1); se += __shfl_xor(se, 2);
                se += __shfl_xor(se, 4); se += __shfl_xor(se, 8);
                sr += __shfl_xor(sr, 1); sr += __shfl_xor(sr, 2);
                sr += __shfl_xor(sr, 4); sr += __shfl_xor(sr, 8);
                int rr = rowb + mt * 16 + r;
                if ((lane & 15) == 0 && rr < M) {
                    elo[rr * 4 + w] = se;
                    ero[rr * 4 + w] = sr;
                }
            }
        }
    }
}

// ---------------- attention score parts (layer 2) ----------------

// val[h*256+k] = sum_j W2[k,h*256+j]*al2[h,j] ; var likewise with ar2
__global__ __launch_bounds__(256) void proj_av_kernel(const float* __restrict__ W2,
                                                      const float* __restrict__ al2,
                                                      const float* __restrict__ ar2,
                                                      float* __restrict__ val,
                                                      float* __restrict__ var_) {
    int gid = blockIdx.x * 256 + threadIdx.x;
    int w = gid >> 6;
    int lane = threadIdx.x & 63;
    if (w >= 1024) return;
    int h = w >> 8, k = w & 255;
    const float* wrow = W2 + (size_t)k * 1024 + h * 256;
    const float* ap = al2 + h * 256;
    const float* rp = ar2 + h * 256;
    float sv = 0.f, sr = 0.f;
    for (int j = lane; j < 256; j += 64) {
        float x = wrow[j];
        sv += x * ap[j];
        sr += x * rp[j];
    }
#pragma unroll
    for (int off = 32; off > 0; off >>= 1) {
        sv += __shfl_down(sv, off);
        sr += __shfl_down(sr, off);
    }
    if (lane == 0) { val[w] = sv; var_[w] = sr; }
}

// el[n,h] = h1[n,:]·val[h,:], er likewise  (fallback when ws too small to fuse)
__global__ __launch_bounds__(256) void elr2_kernel(const float* __restrict__ h1,
                                                   const float* __restrict__ val,
                                                   const float* __restrict__ var_,
                                                   float* __restrict__ el,
                                                   float* __restrict__ er) {
    int gid = blockIdx.x * 256 + threadIdx.x;
    int w = gid >> 6;
    int lane = threadIdx.x & 63;
    if (w >= NN * 4) return;
    int n = w >> 2, h = w & 3;
    const float* hr = h1 + (size_t)n * 256;
    const float* vp = val + h * 256;
    const float* rp = var_ + h * 256;
    float se = 0.f, sr = 0.f;
    for (int k = lane; k < 256; k += 64) {
        float x = hr[k];
        se += x * vp[k];
        sr += x * rp[k];
    }
#pragma unroll
    for (int off = 32; off > 0; off >>= 1) {
        se += __shfl_down(se, off);
        sr += __shfl_down(sr, off);
    }
    if (lane == 0) { el[w] = se; er[w] = sr; }
}

// ---------------- aggregation (R0 baseline structure — do not touch) ----------------

// layer 0: elu epilogue, writes bf16 hi/lo row-major (consumed only by L1 GEMM)

__global__ __launch_bounds__(256) void agg_bf_kernel(const float* __restrict__ z,
                                                     const float* __restrict__ el,
                                                     const float* __restrict__ er,
                                                     const int* __restrict__ offs,
                                                     const int* __restrict__ psrc,
                                                     const float* __restrict__ bias,
                                                     short* __restrict__ ohi,
                                                     short* __restrict__ olo) {
    int n = blockIdx.x;
    int t = threadIdx.x;
    int h = t >> 6;
    __shared__ float p_lds[64][4];
    __shared__ int src_lds[64];
    __shared__ float den_lds[4];
    if (t < 4) den_lds[t] = 0.f;
    int beg = offs[n], end = offs[n + 1];
    float acc = 0.f;
    int e_local = t >> 2, hh = t & 3;
    float er_n = er[n * 4 + hh];
    for (int base = beg; base < end; base += 64) {
        int cnt = min(64, end - base);
        __syncthreads();
        if (e_local < cnt) {
            int s = psrc[base + e_local];
            if (hh == 0) src_lds[e_local] = s;
            float sc = el[s * 4 + hh] + er_n;
            sc = (sc > 0.f) ? sc : 0.2f * sc;
            float p = __expf(sc);
            p_lds[e_local][hh] = p;
            atomicAdd(&den_lds[hh], p);
        }
        __syncthreads();
        for (int e = 0; e < cnt; ++e) {
            acc += p_lds[e][h] * z[(size_t)src_lds[e] * 256 + t];
        }
    }
    __syncthreads();
    float o = acc / fmaxf(den_lds[h], 1e-9f) + bias[t];
    o = (o > 0.f) ? o : (__expf(o) - 1.f);
    short hv, lv;
    split1(o, hv, lv);
    ohi[(size_t)n * 256 + t] = hv;
    olo[(size_t)n * 256 + t] = lv;
}

// layer 1: elu epilogue, fp32 out (consumed by aggH gathers). Optionally fuses
// elr2: el2[n,h] = out[n,:]·val[h,:], er2 likewise (val!=nullptr => fused).

__global__ __launch_bounds__(256) void agg_kernel(const float* __restrict__ z,
                                                  const float* __restrict__ el,
                                                  const float* __restrict__ er,
                                                  const int* __restrict__ offs,
                                                  const int* __restrict__ psrc,
                                                  const float* __restrict__ bias,
                                                  float* __restrict__ out,
                                                  const float* __restrict__ val,
                                                  const float* __restrict__ var_,
                                                  float* __restrict__ el2,
                                                  float* __restrict__ er2) {
    int n = blockIdx.x;
    int t = threadIdx.x;
    int h = t >> 6;
    __shared__ float p_lds[64][4];
    __shared__ int src_lds[64];
    __shared__ float den_lds[4];
    __shared__ float red[4][8];
    if (t < 4) den_lds[t] = 0.f;
    int beg = offs[n], end = offs[n + 1];
    float acc = 0.f;
    int e_local = t >> 2, hh = t & 3;
    float er_n = er[n * 4 + hh];
    for (int base = beg; base < end; base += 64) {
        int cnt = min(64, end - base);
        __syncthreads();
        if (e_local < cnt) {
            int s = psrc[base + e_local];
            if (hh == 0) src_lds[e_local] = s;
            float sc = el[s * 4 + hh] + er_n;
            sc = (sc > 0.f) ? sc : 0.2f * sc;
            float p = __expf(sc);
            p_lds[e_local][hh] = p;
            atomicAdd(&den_lds[hh], p);
        }
        __syncthreads();
        for (int e = 0; e < cnt; ++e) {
            acc += p_lds[e][h] * z[(size_t)src_lds[e] * 256 + t];
        }
    }
    __syncthreads();
    float o = acc / fmaxf(den_lds[h], 1e-9f) + bias[t];
    o = (o > 0.f) ? o : (__expf(o) - 1.f);
    out[(size_t)n * 256 + t] = o;
    if (val) {
        // fused elr2: block-wide dot of o with val/var_ rows (k = t)
        float s0 = o * val[t],        s1 = o * val[256 + t];
        float s2 = o * val[512 + t],  s3 = o * val[768 + t];
        float r0 = o * var_[t],       r1 = o * var_[256 + t];
        float r2 = o * var_[512 + t], r3 = o * var_[768 + t];
#pragma unroll
        for (int off = 32; off > 0; off >>= 1) {
            s0 += __shfl_down(s0, off); s1 += __shfl_down(s1, off);
            s2 += __shfl_down(s2, off); s3 += __shfl_down(s3, off);
            r0 += __shfl_down(r0, off); r1 += __shfl_down(r1, off);
            r2 += __shfl_down(r2, off); r3 += __shfl_down(r3, off);
        }
        int lane = t & 63;
        if (lane == 0) {
            red[h][0] = s0; red[h][1] = s1; red[h][2] = s2; red[h][3] = s3;
            red[h][4] = r0; red[h][5] = r1; red[h][6] = r2; red[h][7] = r3;
        }
        __syncthreads();
        if (t < 8) {
            float sum = red[0][t] + red[1][t] + red[2][t] + red[3][t];
            if (t < 4) el2[n * 4 + t] = sum;
            else       er2[n * 4 + (t - 4)] = sum;
        }
    }
}

// layer-2 aggregation of h1 -> bf16 hi/lo row-major [N,1024] (consumed only by fin GEMM)

__global__ __launch_bounds__(256) void aggH_bf_kernel(const float* __restrict__ h1,
                                                      const float* __restrict__ el,
                                                      const float* __restrict__ er,
                                                      const int* __restrict__ offs,
                                                      const int* __restrict__ psrc,
                                                      short* __restrict__ ohi,
                                                      short* __restrict__ olo) {
    int n = blockIdx.x, t = threadIdx.x;
    __shared__ float p_lds[64][4];
    __shared__ int src_lds[64];
    __shared__ float den_lds[4];
    if (t < 4) den_lds[t] = 0.f;
    int beg = offs[n], end = offs[n + 1];
    float a0 = 0.f, a1 = 0.f, a2 = 0.f, a3 = 0.f;
    int e_local = t >> 2, hh = t & 3;
    float er_n = er[n * 4 + hh];
    for (int base = beg; base < end; base += 64) {
        int cnt = min(64, end - base);
        __syncthreads();
        if (e_local < cnt) {
            int s = psrc[base + e_local];
            if (hh == 0) src_lds[e_local] = s;
            float sc = el[s * 4 + hh] + er_n;
            sc = (sc > 0.f) ? sc : 0.2f * sc;
            float p = __expf(sc);
            p_lds[e_local][hh] = p;
            atomicAdd(&den_lds[hh], p);
        }
        __syncthreads();
        for (int e = 0; e < cnt; ++e) {
            float v = h1[(size_t)src_lds[e] * 256 + t];
            a0 += p_lds[e][0] * v;
            a1 += p_lds[e][1] * v;
            a2 += p_lds[e][2] * v;
            a3 += p_lds[e][3] * v;
        }
    }
    __syncthreads();
    float vals[4];
    vals[0] = a0 / fmaxf(den_lds[0], 1e-9f);
    vals[1] = a1 / fmaxf(den_lds[1], 1e-9f);
    vals[2] = a2 / fmaxf(den_lds[2], 1e-9f);
    vals[3] = a3 / fmaxf(den_lds[3], 1e-9f);
    size_t base_o = (size_t)n * 1024 + t;
#pragma unroll
    for (int h = 0; h < 4; ++h) {
        short hv, lv;
        split1(vals[h], hv, lv);
        ohi[base_o + h * 256] = hv;
        olo[base_o + h * 256] = lv;
    }
}

// ---------------- launch ----------------

extern "C" void kernel_launch(void* const* d_in, const int* in_sizes, int n_in,
                              void* d_out, int out_size, void* d_ws, size_t ws_size,
                              hipStream_t stream) {
    const float* feat = (const float*)d_in[0];
    const float* W0 = (const float*)d_in[1];
    const float* al0 = (const float*)d_in[2];
    const float* ar0 = (const float*)d_in[3];
    const float* b0 = (const float*)d_in[4];
    const float* W1 = (const float*)d_in[5];
    const float* al1 = (const float*)d_in[6];
    const float* ar1 = (const float*)d_in[7];
    const float* b1 = (const float*)d_in[8];
    const float* W2 = (const float*)d_in[9];
    const float* al2 = (const float*)d_in[10];
    const float* ar2 = (const float*)d_in[11];
    const float* b2 = (const float*)d_in[12];
    const int* src = (const int*)d_in[13];
    const int* dst = (const int*)d_in[14];
    float* out = (float*)d_out;

    // ---- workspace layout (~262.5 MB + optional 1.6 MB), time-multiplexed ----
    float* slotA = (float*)d_ws;
    float* z = slotA;                                     // [N,256] fp32
    short* feathi = (short*)(slotA + (size_t)NN * 256);   // 50000*128 shorts
    short* featlo = feathi + (size_t)NN * 128;
    short* Ahi = (short*)slotA;                           // [N,1024] shorts (layer 2)
    short* Alo = Ahi + (size_t)NN * 1024;
    float* slotB = slotA + (size_t)NN * 1024;
    short* h0hi = (short*)slotB;                          // 50000*256 shorts
    short* h0lo = h0hi + (size_t)NN * 256;
    float* h1 = slotB;                                    // [N,256] fp32 (layer 2)
    float* el = slotB + (size_t)NN * 256;                 // 200000
    float* er = el + (size_t)NN * NH_HEADS;               // 200000
    int* deg = (int*)(er + (size_t)NN * NH_HEADS);        // 50000
    int* offs = deg + NN;                                 // 50001 (+1 pad)
    int* cursor = offs + NN + 2;                          // 50000
    int* bsums = cursor + NN;                             // 256
    int* boffs = bsums + 256;                             // 256
    int* psrc = boffs + 256;                              // 800000 (+2 pad)
    short* Bh = (short*)(psrc + NE + 2);                  // 262144 shorts
    short* Bl = Bh + 262144;                              // 262144 shorts
    float* val = (float*)(Bl + 262144);                   // 1024
    float* var_ = val + 1024;                             // 1024
    // separate layer-2 score buffers (el/er stay live during agg_kernel's
    // gather phase, so the fused epilogue must not write over them)
    float* el2 = var_ + 1024;                             // 200000
    float* er2 = el2 + (size_t)NN * NH_HEADS;             // 200000
    size_t need = (size_t)((char*)(er2 + (size_t)NN * NH_HEADS) - (char*)d_ws);
    bool fuse_elr2 = need <= ws_size;

    // ---- CSR build (by dst) ----
    hipMemsetAsync(deg, 0, NN * sizeof(int), stream);
    hist_kernel<<<(NE + 255) / 256, 256, 0, stream>>>(dst, deg, NE);
    int nb = (NN + 255) / 256;
    scan_block_kernel<<<nb, 256, 0, stream>>>(deg, offs, bsums, NN);
    scan_sums_kernel<<<1, 256, 0, stream>>>(bsums, boffs, nb);
    add_offs_kernel<<<nb, 256, 0, stream>>>(offs, boffs, cursor, NN, NE);
    scatter_kernel<<<(NE + 255) / 256, 256, 0, stream>>>(src, dst, cursor, psrc, NE);

    int mb64 = (NN + 63) / 64; // 782

    // ---- layer 0: 128 -> 4x64, elu (elr fused into GEMM epilogue) ----
    splitA_rm<<<(NN * 128 / 8 + 255) / 256, 256, 0, stream>>>(feat, feathi, featlo, NN * 128 / 8);
    splitB_kernel<<<(4096 + 255) / 256, 256, 0, stream>>>(W0, Bh, Bl, 128, 256);
    gemm_n256l<<<mb64, 256, 0, stream>>>(feathi, featlo, Bh, Bl, nullptr, z,
                                         al0, ar0, el, er, NN, 128);
    agg_bf_kernel<<<NN, 256, 0, stream>>>(z, el, er, offs, psrc, b0, h0hi, h0lo);

    // ---- layer 1: 256 -> 4x64, elu (elr fused; elr2 fused into agg) ----
    splitB_kernel<<<(8192 + 255) / 256, 256, 0, stream>>>(W1, Bh, Bl, 256, 256);
    gemm_n256l<<<mb64, 256, 0, stream>>>(h0hi, h0lo, Bh, Bl, nullptr, z,
                                         al1, ar1, el, er, NN, 256);
    proj_av_kernel<<<256, 256, 0, stream>>>(W2, al2, ar2, val, var_);
    agg_kernel<<<NN, 256, 0, stream>>>(z, el, er, offs, psrc, b1, h1,
                                       fuse_elr2 ? val : nullptr, var_, el2, er2);

    // ---- layer 2 (restructured): aggregate h1, then project ----
    const float* elF;
    const float* erF;
    if (fuse_elr2) {
        elF = el2; erF = er2;
    } else {
        elr2_kernel<<<NN, 256, 0, stream>>>(h1, val, var_, el, er);
        elF = el; erF = er;
    }
    aggH_bf_kernel<<<NN, 256, 0, stream>>>(h1, elF, erF, offs, psrc, Ahi, Alo);
    splitB2_kernel<<<(32768 + 255) / 256, 256, 0, stream>>>(W2, Bh, Bl);
    gemm_n256l<<<mb64, 256, 0, stream>>>(Ahi, Alo, Bh, Bl, b2, out,
                                         nullptr, nullptr, nullptr, nullptr, NN, 1024);
}

// Round 7
// 830.684 us; speedup vs baseline: 1.5386x; 1.0051x over previous
//
#include <hip/hip_runtime.h>
#include <hip/hip_bf16.h>

// GAT: 3 layers. N=50000 nodes, E=800000 edges, H=4 heads.
// R7: GEMM = m97-style 2-barrier K-loop, bf16 hi/lo split A/B.
// R8/R10/R11 (FAILED): manual gather restructures (readfirstlane, wave-row,
// col-slice) all reduced in-flight loads or missed L2.
// R13: elr fused into GEMM epilogue, elr2 into agg epilogue. 834.9us.
// R14: the 190us-vs-145us gather split is accumulator ILP: aggH (4 FMA
// chains, VGPR32) hits 4.35TB/s; agg/agg_bf (1 chain, VGPR20) hit 2.4.
// Fix: 4 edge-offset accumulators in agg/agg_bf, tail-free padded slots.
// aggH untouched.

#define NN 50000
#define NE 800000
#define NH_HEADS 4

typedef __attribute__((ext_vector_type(8))) short short8;
typedef __attribute__((ext_vector_type(4))) float floatx4;

__device__ inline float bf2f(short s) {
    union { unsigned u; float f; } v; v.u = ((unsigned)(unsigned short)s) << 16;
    return v.f;
}
__device__ inline short f2bf_rne(float x) {
    union { float f; unsigned u; } v; v.f = x;
    unsigned r = v.u + 0x7fff + ((v.u >> 16) & 1);
    return (short)(r >> 16);
}
// truncation hi/lo split: hi = trunc16(x), lo = trunc16(x - hi)
__device__ inline void split1(float x, short& h, short& l) {
    union { float f; unsigned u; } v; v.f = x;
    h = (short)(v.u >> 16);
    union { float f; unsigned u; } rv; rv.f = v.f - bf2f(h);
    l = (short)(rv.u >> 16);
}

// async 16B/lane global->LDS; lds base must be wave-uniform (dest = base + lane*16)
__device__ inline void load_lds16(const short* g, short* l) {
    __builtin_amdgcn_global_load_lds(
        (const __attribute__((address_space(1))) void*)g,
        (__attribute__((address_space(3))) void*)l, 16, 0, 0);
}

// ---------------- CSR build ----------------

__global__ void hist_kernel(const int* __restrict__ dst, int* __restrict__ deg, int E) {
    int e = blockIdx.x * 256 + threadIdx.x;
    if (e < E) atomicAdd(&deg[dst[e]], 1);
}

__global__ void scan_block_kernel(const int* __restrict__ deg, int* __restrict__ offs,
                                  int* __restrict__ bsums, int n) {
    __shared__ int s[256];
    int tid = threadIdx.x;
    int i = blockIdx.x * 256 + tid;
    int v = (i < n) ? deg[i] : 0;
    s[tid] = v;
    __syncthreads();
    for (int off = 1; off < 256; off <<= 1) {
        int x = (tid >= off) ? s[tid - off] : 0;
        __syncthreads();
        s[tid] += x;
        __syncthreads();
    }
    if (i < n) offs[i] = s[tid] - v;
    if (tid == 255) bsums[blockIdx.x] = s[255];
}

__global__ void scan_sums_kernel(const int* __restrict__ bsums, int* __restrict__ boffs, int nb) {
    __shared__ int s[256];
    int tid = threadIdx.x;
    int v = (tid < nb) ? bsums[tid] : 0;
    s[tid] = v;
    __syncthreads();
    for (int off = 1; off < 256; off <<= 1) {
        int x = (tid >= off) ? s[tid - off] : 0;
        __syncthreads();
        s[tid] += x;
        __syncthreads();
    }
    boffs[tid] = s[tid] - v;
}

__global__ void add_offs_kernel(int* __restrict__ offs, const int* __restrict__ boffs,
                                int* __restrict__ cursor, int n, int total) {
    int i = blockIdx.x * 256 + threadIdx.x;
    if (i < n) {
        int o = offs[i] + boffs[blockIdx.x];
        offs[i] = o;
        cursor[i] = o;
    }
    if (i == 0) offs[n] = total;
}

__global__ void scatter_kernel(const int* __restrict__ src, const int* __restrict__ dst,
                               int* __restrict__ cursor, int* __restrict__ psrc, int E) {
    int e = blockIdx.x * 256 + threadIdx.x;
    if (e < E) {
        int p = atomicAdd(&cursor[dst[e]], 1);
        psrc[p] = src[e];
    }
}

// ---------------- A (row-major fp32) -> row-major bf16 hi/lo ----------------

__global__ __launch_bounds__(256) void splitA_rm(const float* __restrict__ A,
                                                 short* __restrict__ hi,
                                                 short* __restrict__ lo,
                                                 int total8) {
    int tid = blockIdx.x * 256 + threadIdx.x;
    if (tid >= total8) return;
    const float* p = A + (size_t)tid * 8;
    float4 x0 = ((const float4*)p)[0];
    float4 x1 = ((const float4*)p)[1];
    float xs[8] = {x0.x, x0.y, x0.z, x0.w, x1.x, x1.y, x1.z, x1.w};
    short8 hv, lv;
#pragma unroll
    for (int j = 0; j < 8; ++j) { short h, l; split1(xs[j], h, l); hv[j] = h; lv[j] = l; }
    ((short8*)hi)[tid] = hv;
    ((short8*)lo)[tid] = lv;
}

// ---------------- B -> bf16 hi/lo in MFMA B-fragment order ----------------
// offset (short8) = (c*(N/16)+g)*64 + lane ; lane=(n&15)+16*((k&31)>>3), j=k&7

__global__ __launch_bounds__(256) void splitB_kernel(const float* __restrict__ B,
                                                     short* __restrict__ hi,
                                                     short* __restrict__ lo,
                                                     int K, int N) {
    int tid = blockIdx.x * 256 + threadIdx.x;
    int NG = N >> 4;
    int total = (K >> 5) * NG * 64;
    if (tid >= total) return;
    int lane = tid & 63;
    int rc = tid >> 6;
    int g = rc % NG, c = rc / NG;
    int n = g * 16 + (lane & 15);
    int k = c * 32 + (lane >> 4) * 8;
    short8 hv, lv;
#pragma unroll
    for (int j = 0; j < 8; ++j) {
        float x = B[(size_t)(k + j) * N + n];
        short h = f2bf_rne(x);
        hv[j] = h;
        lv[j] = f2bf_rne(x - bf2f(h));
    }
    ((short8*)hi)[tid] = hv;
    ((short8*)lo)[tid] = lv;
}

// permuted-W2: Bp[h*256+k, c] = W2[k, h*256+c]; K=1024, N=256
__global__ __launch_bounds__(256) void splitB2_kernel(const float* __restrict__ W2,
                                                      short* __restrict__ hi,
                                                      short* __restrict__ lo) {
    int tid = blockIdx.x * 256 + threadIdx.x;
    const int NG = 16;
    int total = (1024 >> 5) * NG * 64;   // 32768
    if (tid >= total) return;
    int lane = tid & 63;
    int rc = tid >> 6;
    int g = rc % NG, c = rc / NG;
    int n = g * 16 + (lane & 15);
    int kk = c * 32 + (lane >> 4) * 8;
    short8 hv, lv;
#pragma unroll
    for (int j = 0; j < 8; ++j) {
        int kg = kk + j;
        int h = kg >> 8, k = kg & 255;
        float x = W2[(size_t)k * 1024 + h * 256 + n];
        short hb = f2bf_rne(x);
        hv[j] = hb;
        lv[j] = f2bf_rne(x - bf2f(hb));
    }
    ((short8*)hi)[tid] = hv;
    ((short8*)lo)[tid] = lv;
}

// ---------------- MFMA GEMM, N=256, A via async LDS staging ----------------
// block: 64 rows x 256 cols; wave w owns rows [bm,bm+64) x cols [w*64,(w+1)*64).
// Optional fused elr epilogue (alv!=null): wave w = head w computes
// el[n,w] = z[n, w*64..w*64+64) . alv[w], er likewise, via 4 FMA +
// 4-step shfl_xor reduce over the 16-lane col group per row.

__device__ inline floatx4 mfma16(short8 a, short8 b, floatx4 c) {
    return __builtin_amdgcn_mfma_f32_16x16x32_bf16(a, b, c, 0, 0, 0);
}

__global__ __launch_bounds__(256) void gemm_n256l(const short* __restrict__ Ahi,
                                                  const short* __restrict__ Alo,
                                                  const short* __restrict__ Bh,
                                                  const short* __restrict__ Bl,
                                                  const float* __restrict__ bias4,
                                                  float* __restrict__ C,
                                                  const float* __restrict__ alv,
                                                  const float* __restrict__ arv,
                                                  float* __restrict__ elo,
                                                  float* __restrict__ ero,
                                                  int M, int K) {
    int KC = K >> 5;
    __shared__ short AhL[2048];   // 4 m-tiles x 64 lanes x 8 shorts = 4 KB
    __shared__ short AlL[2048];
    int t = threadIdx.x;
    int lane = t & 63;
    int w = t >> 6;
    int bm = blockIdx.x * 64;
    int g0 = w * 4;
    const short8* pBh = (const short8*)Bh;
    const short8* pBl = (const short8*)Bl;

    floatx4 acc[4][4] = {};

    // staging source for this lane (m-tile w)
    int row = bm + (w << 4) + (lane & 15);
    if (row >= M) row = M - 1;                    // clamp: junk rows never stored
    const short* gh = Ahi + (size_t)row * K + ((lane >> 4) << 3);
    const short* gl = Alo + (size_t)row * K + ((lane >> 4) << 3);
    short* lh = AhL + w * 512;                    // wave-uniform LDS base
    short* ll = AlL + w * 512;

    for (int c = 0; c < KC; ++c) {
        load_lds16(gh + (size_t)c * 32, lh);
        load_lds16(gl + (size_t)c * 32, ll);
        short8 bh[4], bl[4];
#pragma unroll
        for (int g = 0; g < 4; ++g) {
            bh[g] = pBh[((size_t)c * (256 / 16) + g0 + g) * 64 + lane];
            bl[g] = pBl[((size_t)c * (256 / 16) + g0 + g) * 64 + lane];
        }
        __syncthreads();   // drains vmcnt: LDS staged, B regs ready
#pragma unroll
        for (int mt = 0; mt < 4; ++mt) {
            short8 ah = *(const short8*)(AhL + mt * 512 + lane * 8);
            short8 al = *(const short8*)(AlL + mt * 512 + lane * 8);
#pragma unroll
            for (int g = 0; g < 4; ++g) {
                acc[mt][g] = mfma16(ah, bh[g], acc[mt][g]);
                acc[mt][g] = mfma16(al, bh[g], acc[mt][g]);
                acc[mt][g] = mfma16(ah, bl[g], acc[mt][g]);
            }
        }
        __syncthreads();   // all LDS reads done before next overwrite
    }

    // C/D layout: col = lane&15, row = (lane>>4)*4 + reg
    int rowb = bm + (lane >> 4) * 4;
    int colb = w * 64 + (lane & 15);
#pragma unroll
    for (int mt = 0; mt < 4; ++mt) {
#pragma unroll
        for (int r = 0; r < 4; ++r) {
            int rr = rowb + mt * 16 + r;
            if (rr < M) {
#pragma unroll
                for (int g = 0; g < 4; ++g) {
                    int col = colb + g * 16;
                    float v = acc[mt][g][r];
                    if (bias4) {
                        v = 0.25f * (v + bias4[col] + bias4[col + 256] +
                                     bias4[col + 512] + bias4[col + 768]);
                    }
                    C[(size_t)rr * 256 + col] = v;
                }
            }
        }
    }

    // fused elr: el[rr,w] = sum_f z[rr, w*64+f]*alv[w*64+f] (f = (lane&15)+g*16)
    if (alv) {
        float alr[4], arr_[4];
#pragma unroll
        for (int g = 0; g < 4; ++g) {
            int f = w * 64 + (lane & 15) + g * 16;
            alr[g] = alv[f];
            arr_[g] = arv[f];
        }
#pragma unroll
        for (int mt = 0; mt < 4; ++mt) {
#pragma unroll
            for (int r = 0; r < 4; ++r) {
                float se = acc[mt][0][r] * alr[0] + acc[mt][1][r] * alr[1] +
                           acc[mt][2][r] * alr[2] + acc[mt][3][r] * alr[3];
                float sr = acc[mt][0][r] * arr_[0] + acc[mt][1][r] * arr_[1] +
                           acc[mt][2][r] * arr_[2] + acc[mt][3][r] * arr_[3];
                se += __shfl_xor(se, 1); se += __shfl_xor(se, 2);
                se += __shfl_xor(se, 4); se += __shfl_xor(se, 8);
                sr += __shfl_xor(sr, 1); sr += __shfl_xor(sr, 2);
                sr += __shfl_xor(sr, 4); sr += __shfl_xor(sr, 8);
                int rr = rowb + mt * 16 + r;
                if ((lane & 15) == 0 && rr < M) {
                    elo[rr * 4 + w] = se;
                    ero[rr * 4 + w] = sr;
                }
            }
        }
    }
}

// ---------------- attention score parts (layer 2) ----------------

// val[h*256+k] = sum_j W2[k,h*256+j]*al2[h,j] ; var likewise with ar2
__global__ __launch_bounds__(256) void proj_av_kernel(const float* __restrict__ W2,
                                                      const float* __restrict__ al2,
                                                      const float* __restrict__ ar2,
                                                      float* __restrict__ val,
                                                      float* __restrict__ var_) {
    int gid = blockIdx.x * 256 + threadIdx.x;
    int w = gid >> 6;
    int lane = threadIdx.x & 63;
    if (w >= 1024) return;
    int h = w >> 8, k = w & 255;
    const float* wrow = W2 + (size_t)k * 1024 + h * 256;
    const float* ap = al2 + h * 256;
    const float* rp = ar2 + h * 256;
    float sv = 0.f, sr = 0.f;
    for (int j = lane; j < 256; j += 64) {
        float x = wrow[j];
        sv += x * ap[j];
        sr += x * rp[j];
    }
#pragma unroll
    for (int off = 32; off > 0; off >>= 1) {
        sv += __shfl_down(sv, off);
        sr += __shfl_down(sr, off);
    }
    if (lane == 0) { val[w] = sv; var_[w] = sr; }
}

// el[n,h] = h1[n,:]·val[h,:], er likewise  (fallback when ws too small to fuse)
__global__ __launch_bounds__(256) void elr2_kernel(const float* __restrict__ h1,
                                                   const float* __restrict__ val,
                                                   const float* __restrict__ var_,
                                                   float* __restrict__ el,
                                                   float* __restrict__ er) {
    int gid = blockIdx.x * 256 + threadIdx.x;
    int w = gid >> 6;
    int lane = threadIdx.x & 63;
    if (w >= NN * 4) return;
    int n = w >> 2, h = w & 3;
    const float* hr = h1 + (size_t)n * 256;
    const float* vp = val + h * 256;
    const float* rp = var_ + h * 256;
    float se = 0.f, sr = 0.f;
    for (int k = lane; k < 256; k += 64) {
        float x = hr[k];
        se += x * vp[k];
        sr += x * rp[k];
    }
#pragma unroll
    for (int off = 32; off > 0; off >>= 1) {
        se += __shfl_down(se, off);
        sr += __shfl_down(sr, off);
    }
    if (lane == 0) { el[w] = se; er[w] = sr; }
}

// ---------------- aggregation ----------------
// Gather loops: 4 independent edge-offset accumulator chains (the aggH
// pattern that sustains 4.35TB/s). All 64 p/src slots written each chunk
// (p=0,s=0 past cnt) so the 4-wide loop is tail-free; row 0 is valid memory.

// layer 0: elu epilogue, writes bf16 hi/lo row-major (consumed only by L1 GEMM)

__global__ __launch_bounds__(256) void agg_bf_kernel(const float* __restrict__ z,
                                                     const float* __restrict__ el,
                                                     const float* __restrict__ er,
                                                     const int* __restrict__ offs,
                                                     const int* __restrict__ psrc,
                                                     const float* __restrict__ bias,
                                                     short* __restrict__ ohi,
                                                     short* __restrict__ olo) {
    int n = blockIdx.x;
    int t = threadIdx.x;
    int h = t >> 6;
    __shared__ float p_lds[64][4];
    __shared__ int src_lds[64];
    __shared__ float den_lds[4];
    if (t < 4) den_lds[t] = 0.f;
    int beg = offs[n], end = offs[n + 1];
    float a0 = 0.f, a1 = 0.f, a2 = 0.f, a3 = 0.f;
    int e_local = t >> 2, hh = t & 3;
    float er_n = er[n * 4 + hh];
    for (int base = beg; base < end; base += 64) {
        int cnt = min(64, end - base);
        __syncthreads();
        float p = 0.f; int s = 0;
        if (e_local < cnt) {
            s = psrc[base + e_local];
            float sc = el[s * 4 + hh] + er_n;
            sc = (sc > 0.f) ? sc : 0.2f * sc;
            p = __expf(sc);
            atomicAdd(&den_lds[hh], p);
        }
        if (hh == 0) src_lds[e_local] = s;
        p_lds[e_local][hh] = p;
        __syncthreads();
        int cnt4 = (cnt + 3) & ~3;
        for (int e = 0; e < cnt4; e += 4) {
            a0 += p_lds[e][h]     * z[(size_t)src_lds[e] * 256 + t];
            a1 += p_lds[e + 1][h] * z[(size_t)src_lds[e + 1] * 256 + t];
            a2 += p_lds[e + 2][h] * z[(size_t)src_lds[e + 2] * 256 + t];
            a3 += p_lds[e + 3][h] * z[(size_t)src_lds[e + 3] * 256 + t];
        }
    }
    __syncthreads();
    float acc = (a0 + a1) + (a2 + a3);
    float o = acc / fmaxf(den_lds[h], 1e-9f) + bias[t];
    o = (o > 0.f) ? o : (__expf(o) - 1.f);
    short hv, lv;
    split1(o, hv, lv);
    ohi[(size_t)n * 256 + t] = hv;
    olo[(size_t)n * 256 + t] = lv;
}

// layer 1: elu epilogue, fp32 out (consumed by aggH gathers). Optionally fuses
// elr2: el2[n,h] = out[n,:]·val[h,:], er2 likewise (val!=nullptr => fused).

__global__ __launch_bounds__(256) void agg_kernel(const float* __restrict__ z,
                                                  const float* __restrict__ el,
                                                  const float* __restrict__ er,
                                                  const int* __restrict__ offs,
                                                  const int* __restrict__ psrc,
                                                  const float* __restrict__ bias,
                                                  float* __restrict__ out,
                                                  const float* __restrict__ val,
                                                  const float* __restrict__ var_,
                                                  float* __restrict__ el2,
                                                  float* __restrict__ er2) {
    int n = blockIdx.x;
    int t = threadIdx.x;
    int h = t >> 6;
    __shared__ float p_lds[64][4];
    __shared__ int src_lds[64];
    __shared__ float den_lds[4];
    __shared__ float red[4][8];
    if (t < 4) den_lds[t] = 0.f;
    int beg = offs[n], end = offs[n + 1];
    float a0 = 0.f, a1 = 0.f, a2 = 0.f, a3 = 0.f;
    int e_local = t >> 2, hh = t & 3;
    float er_n = er[n * 4 + hh];
    for (int base = beg; base < end; base += 64) {
        int cnt = min(64, end - base);
        __syncthreads();
        float p = 0.f; int s = 0;
        if (e_local < cnt) {
            s = psrc[base + e_local];
            float sc = el[s * 4 + hh] + er_n;
            sc = (sc > 0.f) ? sc : 0.2f * sc;
            p = __expf(sc);
            atomicAdd(&den_lds[hh], p);
        }
        if (hh == 0) src_lds[e_local] = s;
        p_lds[e_local][hh] = p;
        __syncthreads();
        int cnt4 = (cnt + 3) & ~3;
        for (int e = 0; e < cnt4; e += 4) {
            a0 += p_lds[e][h]     * z[(size_t)src_lds[e] * 256 + t];
            a1 += p_lds[e + 1][h] * z[(size_t)src_lds[e + 1] * 256 + t];
            a2 += p_lds[e + 2][h] * z[(size_t)src_lds[e + 2] * 256 + t];
            a3 += p_lds[e + 3][h] * z[(size_t)src_lds[e + 3] * 256 + t];
        }
    }
    __syncthreads();
    float acc = (a0 + a1) + (a2 + a3);
    float o = acc / fmaxf(den_lds[h], 1e-9f) + bias[t];
    o = (o > 0.f) ? o : (__expf(o) - 1.f);
    out[(size_t)n * 256 + t] = o;
    if (val) {
        // fused elr2: block-wide dot of o with val/var_ rows (k = t)
        float s0 = o * val[t],        s1 = o * val[256 + t];
        float s2 = o * val[512 + t],  s3 = o * val[768 + t];
        float r0 = o * var_[t],       r1 = o * var_[256 + t];
        float r2 = o * var_[512 + t], r3 = o * var_[768 + t];
#pragma unroll
        for (int off = 32; off > 0; off >>= 1) {
            s0 += __shfl_down(s0, off); s1 += __shfl_down(s1, off);
            s2 += __shfl_down(s2, off); s3 += __shfl_down(s3, off);
            r0 += __shfl_down(r0, off); r1 += __shfl_down(r1, off);
            r2 += __shfl_down(r2, off); r3 += __shfl_down(r3, off);
        }
        int lane = t & 63;
        if (lane == 0) {
            red[h][0] = s0; red[h][1] = s1; red[h][2] = s2; red[h][3] = s3;
            red[h][4] = r0; red[h][5] = r1; red[h][6] = r2; red[h][7] = r3;
        }
        __syncthreads();
        if (t < 8) {
            float sum = red[0][t] + red[1][t] + red[2][t] + red[3][t];
            if (t < 4) el2[n * 4 + t] = sum;
            else       er2[n * 4 + (t - 4)] = sum;
        }
    }
}

// layer-2 aggregation of h1 -> bf16 hi/lo row-major [N,1024] (consumed only by fin GEMM)

__global__ __launch_bounds__(256) void aggH_bf_kernel(const float* __restrict__ h1,
                                                      const float* __restrict__ el,
                                                      const float* __restrict__ er,
                                                      const int* __restrict__ offs,
                                                      const int* __restrict__ psrc,
                                                      short* __restrict__ ohi,
                                                      short* __restrict__ olo) {
    int n = blockIdx.x, t = threadIdx.x;
    __shared__ float p_lds[64][4];
    __shared__ int src_lds[64];
    __shared__ float den_lds[4];
    if (t < 4) den_lds[t] = 0.f;
    int beg = offs[n], end = offs[n + 1];
    float a0 = 0.f, a1 = 0.f, a2 = 0.f, a3 = 0.f;
    int e_local = t >> 2, hh = t & 3;
    float er_n = er[n * 4 + hh];
    for (int base = beg; base < end; base += 64) {
        int cnt = min(64, end - base);
        __syncthreads();
        if (e_local < cnt) {
            int s = psrc[base + e_local];
            if (hh == 0) src_lds[e_local] = s;
            float sc = el[s * 4 + hh] + er_n;
            sc = (sc > 0.f) ? sc : 0.2f * sc;
            float p = __expf(sc);
            p_lds[e_local][hh] = p;
            atomicAdd(&den_lds[hh], p);
        }
        __syncthreads();
        for (int e = 0; e < cnt; ++e) {
            float v = h1[(size_t)src_lds[e] * 256 + t];
            a0 += p_lds[e][0] * v;
            a1 += p_lds[e][1] * v;
            a2 += p_lds[e][2] * v;
            a3 += p_lds[e][3] * v;
        }
    }
    __syncthreads();
    float vals[4];
    vals[0] = a0 / fmaxf(den_lds[0], 1e-9f);
    vals[1] = a1 / fmaxf(den_lds[1], 1e-9f);
    vals[2] = a2 / fmaxf(den_lds[2], 1e-9f);
    vals[3] = a3 / fmaxf(den_lds[3], 1e-9f);
    size_t base_o = (size_t)n * 1024 + t;
#pragma unroll
    for (int h = 0; h < 4; ++h) {
        short hv, lv;
        split1(vals[h], hv, lv);
        ohi[base_o + h * 256] = hv;
        olo[base_o + h * 256] = lv;
    }
}

// ---------------- launch ----------------

extern "C" void kernel_launch(void* const* d_in, const int* in_sizes, int n_in,
                              void* d_out, int out_size, void* d_ws, size_t ws_size,
                              hipStream_t stream) {
    const float* feat = (const float*)d_in[0];
    const float* W0 = (const float*)d_in[1];
    const float* al0 = (const float*)d_in[2];
    const float* ar0 = (const float*)d_in[3];
    const float* b0 = (const float*)d_in[4];
    const float* W1 = (const float*)d_in[5];
    const float* al1 = (const float*)d_in[6];
    const float* ar1 = (const float*)d_in[7];
    const float* b1 = (const float*)d_in[8];
    const float* W2 = (const float*)d_in[9];
    const float* al2 = (const float*)d_in[10];
    const float* ar2 = (const float*)d_in[11];
    const float* b2 = (const float*)d_in[12];
    const int* src = (const int*)d_in[13];
    const int* dst = (const int*)d_in[14];
    float* out = (float*)d_out;

    // ---- workspace layout (~262.5 MB + optional 1.6 MB), time-multiplexed ----
    float* slotA = (float*)d_ws;
    float* z = slotA;                                     // [N,256] fp32
    short* feathi = (short*)(slotA + (size_t)NN * 256);   // 50000*128 shorts
    short* featlo = feathi + (size_t)NN * 128;
    short* Ahi = (short*)slotA;                           // [N,1024] shorts (layer 2)
    short* Alo = Ahi + (size_t)NN * 1024;
    float* slotB = slotA + (size_t)NN * 1024;
    short* h0hi = (short*)slotB;                          // 50000*256 shorts
    short* h0lo = h0hi + (size_t)NN * 256;
    float* h1 = slotB;                                    // [N,256] fp32 (layer 2)
    float* el = slotB + (size_t)NN * 256;                 // 200000
    float* er = el + (size_t)NN * NH_HEADS;               // 200000
    int* deg = (int*)(er + (size_t)NN * NH_HEADS);        // 50000
    int* offs = deg + NN;                                 // 50001 (+1 pad)
    int* cursor = offs + NN + 2;                          // 50000
    int* bsums = cursor + NN;                             // 256
    int* boffs = bsums + 256;                             // 256
    int* psrc = boffs + 256;                              // 800000 (+2 pad)
    short* Bh = (short*)(psrc + NE + 2);                  // 262144 shorts
    short* Bl = Bh + 262144;                              // 262144 shorts
    float* val = (float*)(Bl + 262144);                   // 1024
    float* var_ = val + 1024;                             // 1024
    // separate layer-2 score buffers (el/er stay live during agg_kernel's
    // gather phase, so the fused epilogue must not write over them)
    float* el2 = var_ + 1024;                             // 200000
    float* er2 = el2 + (size_t)NN * NH_HEADS;             // 200000
    size_t need = (size_t)((char*)(er2 + (size_t)NN * NH_HEADS) - (char*)d_ws);
    bool fuse_elr2 = need <= ws_size;

    // ---- CSR build (by dst) ----
    hipMemsetAsync(deg, 0, NN * sizeof(int), stream);
    hist_kernel<<<(NE + 255) / 256, 256, 0, stream>>>(dst, deg, NE);
    int nb = (NN + 255) / 256;
    scan_block_kernel<<<nb, 256, 0, stream>>>(deg, offs, bsums, NN);
    scan_sums_kernel<<<1, 256, 0, stream>>>(bsums, boffs, nb);
    add_offs_kernel<<<nb, 256, 0, stream>>>(offs, boffs, cursor, NN, NE);
    scatter_kernel<<<(NE + 255) / 256, 256, 0, stream>>>(src, dst, cursor, psrc, NE);

    int mb64 = (NN + 63) / 64; // 782

    // ---- layer 0: 128 -> 4x64, elu (elr fused into GEMM epilogue) ----
    splitA_rm<<<(NN * 128 / 8 + 255) / 256, 256, 0, stream>>>(feat, feathi, featlo, NN * 128 / 8);
    splitB_kernel<<<(4096 + 255) / 256, 256, 0, stream>>>(W0, Bh, Bl, 128, 256);
    gemm_n256l<<<mb64, 256, 0, stream>>>(feathi, featlo, Bh, Bl, nullptr, z,
                                         al0, ar0, el, er, NN, 128);
    agg_bf_kernel<<<NN, 256, 0, stream>>>(z, el, er, offs, psrc, b0, h0hi, h0lo);

    // ---- layer 1: 256 -> 4x64, elu (elr fused; elr2 fused into agg) ----
    splitB_kernel<<<(8192 + 255) / 256, 256, 0, stream>>>(W1, Bh, Bl, 256, 256);
    gemm_n256l<<<mb64, 256, 0, stream>>>(h0hi, h0lo, Bh, Bl, nullptr, z,
                                         al1, ar1, el, er, NN, 256);
    proj_av_kernel<<<256, 256, 0, stream>>>(W2, al2, ar2, val, var_);
    agg_kernel<<<NN, 256, 0, stream>>>(z, el, er, offs, psrc, b1, h1,
                                       fuse_elr2 ? val : nullptr, var_, el2, er2);

    // ---- layer 2 (restructured): aggregate h1, then project ----
    const float* elF;
    const float* erF;
    if (fuse_elr2) {
        elF = el2; erF = er2;
    } else {
        elr2_kernel<<<NN, 256, 0, stream>>>(h1, val, var_, el, er);
        elF = el; erF = er;
    }
    aggH_bf_kernel<<<NN, 256, 0, stream>>>(h1, elF, erF, offs, psrc, Ahi, Alo);
    splitB2_kernel<<<(32768 + 255) / 256, 256, 0, stream>>>(W2, Bh, Bl);
    gemm_n256l<<<mb64, 256, 0, stream>>>(Ahi, Alo, Bh, Bl, b2, out,
                                         nullptr, nullptr, nullptr, nullptr, NN, 1024);
}